// Round 6
// baseline (430.676 us; speedup 1.0000x reference)
//
#include <hip/hip_runtime.h>
#include <hip/hip_fp16.h>
#include <cstddef>

// Problem constants (match reference)
#define N_NODES 100000
#define N_EDGES 1600000
#define E_TOT   (N_EDGES + N_NODES)   // edges + self loops = 1,700,000
#define IN_DIM  64
#define HIDDEN  128
#define Z_DIM   64

// dst-buckets for locality-preserving fill
#define BN 128
#define NB ((N_NODES + BN - 1) / BN)   // 782
#define NBLK 256                        // chunk blocks for binA

using f16x8 = __attribute__((ext_vector_type(8))) _Float16;
using f32x4 = __attribute__((ext_vector_type(4))) float;

// ---------------- CSR build ----------------

// per-node degree count: 1.6M fire-and-forget atomics over 100K addresses (proven cheap)
__global__ __launch_bounds__(256) void count_k(const int* __restrict__ dst, int* cnt, int e) {
    int i = blockIdx.x * 256 + threadIdx.x;
    if (i < e) atomicAdd(&cnt[dst[i]], 1);
}

// block-level exclusive scan of (cnt+1) -> rowptr (+ per-block sums); emits dinv = rsqrt(deg)
__global__ __launch_bounds__(256) void scan_block_k(const int* __restrict__ cnt, int* __restrict__ rowptr,
                                                    int* __restrict__ bsum, float* __restrict__ dinv, int n) {
    __shared__ int s[256];
    int tid = threadIdx.x;
    int i = blockIdx.x * 256 + tid;
    int v = (i < n) ? cnt[i] + 1 : 0;         // +1 self loop
    if (i < n) dinv[i] = rsqrtf((float)v);
    s[tid] = v;
    __syncthreads();
#pragma unroll
    for (int off = 1; off < 256; off <<= 1) {
        int t = (tid >= off) ? s[tid - off] : 0;
        __syncthreads();
        s[tid] += t;
        __syncthreads();
    }
    if (i < n) rowptr[i] = s[tid] - v;        // exclusive within block
    if (tid == 255) bsum[blockIdx.x] = s[255];
}

__global__ __launch_bounds__(512) void scan_bsum_k(int* bsum, int nb) {
    __shared__ int s[512];
    int tid = threadIdx.x;
    int v = (tid < nb) ? bsum[tid] : 0;
    s[tid] = v;
    __syncthreads();
#pragma unroll
    for (int off = 1; off < 512; off <<= 1) {
        int t = (tid >= off) ? s[tid - off] : 0;
        __syncthreads();
        s[tid] += t;
        __syncthreads();
    }
    if (tid < nb) bsum[tid] = s[tid] - v;     // exclusive
}

// add block sums; also emit bucket edge-space bases: ebase[b] = rowptr[b*BN] - b*BN
__global__ __launch_bounds__(256) void scan_add_k(int* __restrict__ rowptr, const int* __restrict__ bsum,
                                                  int* __restrict__ ebase, int* __restrict__ bcur,
                                                  int n, int etot, int e) {
    int i = blockIdx.x * 256 + threadIdx.x;
    if (i < n) {
        int val = rowptr[i] + bsum[blockIdx.x];
        rowptr[i] = val;
        if ((i & (BN - 1)) == 0) {
            int b = i >> 7;
            int eb = val - b * BN;
            ebase[b] = eb;
            bcur[b] = eb;
        }
    }
    if (i == 0) { rowptr[n] = etot; ebase[NB] = e; }
}

// Phase A: chunked binning. LDS bucket-hist per block; ONE with-return global atomic per
// (block,bucket) (200K total — no contention stall); place chunk into bucket-contiguous
// binned[] via LDS cursors. Packed 4B: {local_dst(7b) << 17 | src(17b)}.
__global__ __launch_bounds__(256) void binA_k(const int* __restrict__ src, const int* __restrict__ dst,
                                              int* __restrict__ bcur, int* __restrict__ binned, int e) {
    __shared__ int hist[NB];
    __shared__ int cur[NB];
    int t = threadIdx.x;
    int ch = (e + gridDim.x - 1) / gridDim.x;
    int i0 = blockIdx.x * ch;
    int i1 = i0 + ch; if (i1 > e) i1 = e;

    for (int b = t; b < NB; b += 256) hist[b] = 0;
    __syncthreads();
    for (int i = i0 + t; i < i1; i += 256)
        atomicAdd(&hist[dst[i] >> 7], 1);
    __syncthreads();
    for (int b = t; b < NB; b += 256) {
        int h = hist[b];
        cur[b] = h ? atomicAdd(&bcur[b], h) : 0;
    }
    __syncthreads();
    for (int i = i0 + t; i < i1; i += 256) {
        int s = src[i], d = dst[i];
        int p = atomicAdd(&cur[d >> 7], 1);
        binned[p] = ((d & 127) << 17) | s;
    }
}

// Phase B: one block per bucket. Per-node LDS cursors seeded from rowptr; all em writes
// for the bucket's ~14KB region come from ONE CU -> full-line merge in its L2.
// Emits packed {src, normbits}: norm = dinv[src]*dinv[dst] (dst-dinv staged in LDS).
__global__ __launch_bounds__(256) void place_k(const int* __restrict__ binned, const int* __restrict__ ebase,
                                               const int* __restrict__ rowptr, const float* __restrict__ dinv,
                                               int2* __restrict__ em, int n) {
    __shared__ int cur[BN];
    __shared__ float sdv[BN];
    int b = blockIdx.x, t = threadIdx.x;
    int n0 = b * BN;
    int nn = n - n0; if (nn > BN) nn = BN;
    if (t < nn) {
        int rp = rowptr[n0 + t];
        float dv = dinv[n0 + t];
        sdv[t] = dv;
        em[rp] = make_int2(n0 + t, __float_as_int(dv * dv));   // self loop first
        cur[t] = rp + 1;
    }
    __syncthreads();
    int e0 = ebase[b], e1 = ebase[b + 1];
    for (int i = e0 + t; i < e1; i += 256) {
        int pk = binned[i];
        int ld = pk >> 17, s = pk & 0x1FFFF;
        int q = atomicAdd(&cur[ld], 1);
        em[q] = make_int2(s, __float_as_int(dinv[s] * sdv[ld]));
    }
}

// cast fp32 -> fp16, 8 elems per thread (total must be divisible by 8)
__global__ __launch_bounds__(256) void cast16_k(const float* __restrict__ in, __half* __restrict__ out, int total8) {
    int i = blockIdx.x * 256 + threadIdx.x;
    if (i >= total8) return;
    const float4* in4 = (const float4*)in;
    float4 a = in4[2 * i], b = in4[2 * i + 1];
    __half2 h0 = __floats2half2_rn(a.x, a.y);
    __half2 h1 = __floats2half2_rn(a.z, a.w);
    __half2 h2 = __floats2half2_rn(b.x, b.y);
    __half2 h3 = __floats2half2_rn(b.z, b.w);
    uint4 pk = make_uint4(*(unsigned*)&h0, *(unsigned*)&h1, *(unsigned*)&h2, *(unsigned*)&h3);
    ((uint4*)out)[i] = pk;
}

// one-time W prep: transpose + fp16 cast. W1t[col][k] (128x64), W2t (128x128),
// Wht (128x128: col<64 <- Wmu, col>=64 <- Wlv). Total 40960 elems — trivial.
__global__ __launch_bounds__(256) void wprep_k(const float* __restrict__ W1, const float* __restrict__ W2,
                                               const float* __restrict__ Wmu, const float* __restrict__ Wlv,
                                               __half* __restrict__ W1t, __half* __restrict__ W2t,
                                               __half* __restrict__ Wht) {
    int i = blockIdx.x * 256 + threadIdx.x;
    if (i < 128 * 64) {
        int col = i >> 6, k = i & 63;
        W1t[i] = __float2half(W1[k * 128 + col]);
    }
    int j = i - 128 * 64;
    if (j >= 0 && j < 128 * 128) {
        int col = j >> 7, k = j & 127;
        W2t[j] = __float2half(W2[k * 128 + col]);
    }
    int m = i - 128 * 64 - 128 * 128;
    if (m >= 0 && m < 128 * 128) {
        int col = m >> 7, k = m & 127;
        Wht[m] = __float2half(col < 64 ? Wmu[k * 64 + col] : Wlv[k * 64 + (col - 64)]);
    }
}

// ---------------- Aggregation (gather): fp16 rows, fp32 accumulate ----------------
// One node per wave; granule = 2 slots (STEP edges). 4-phase rotated software pipeline
// (manual unroll-4, zero register moves): body(p) issues rows(g+2), FMAs granule g,
// fetches meta(g+4). Rows and meta each get ~2 bodies of latency cover; 4 row-gathers
// + 2 meta loads in flight per wave at the FMA wait. All prefetches clamp-indexed
// (weight 0 past end) -> branch-free. HEAD: bias + fp32 split store to mu/lv.

template <int DIM, bool HEAD>
__global__ __launch_bounds__(256) void agg_k(const __half* __restrict__ H, const int* __restrict__ rowptr,
                                             const int2* __restrict__ em, __half* __restrict__ out,
                                             const float* __restrict__ bmu, const float* __restrict__ blv,
                                             float* __restrict__ mu, float* __restrict__ lv, int n) {
    int node = (int)((blockIdx.x * 256 + threadIdx.x) >> 6);
    if (node >= n) return;
    int lane = threadIdx.x & 63;
    int beg = rowptr[node], end = rowptr[node + 1];
    const uint4* H4 = (const uint4*)H;

    constexpr int RV   = DIM / 8;            // 16B-chunks per row (128->16, 64->8)
    constexpr int SUBS = 64 / RV;            // parallel edge slots (4 or 8)
    constexpr int STEP = SUBS * 2;           // edges per granule (8 or 16)
    int sub = lane / RV;
    int fl  = lane % RV;

    float acc[8];
#pragma unroll
    for (int q = 0; q < 8; q++) acc[q] = 0.f;

    auto meta = [&](int j, int p, int& s, float& w) {
        int idx = j + SUBS * p + sub;
        int ci  = idx < end ? idx : beg;
        int2 e  = em[ci];
        s = e.x;
        w = idx < end ? __int_as_float(e.y) : 0.f;
    };
    auto rows = [&](int s0, int s1, uint4& r0, uint4& r1) {
        r0 = H4[(size_t)s0 * RV + fl];
        r1 = H4[(size_t)s1 * RV + fl];
    };
    auto fmas = [&](const uint4& r0, const uint4& r1, float ww0, float ww1) {
        const __half* h0 = (const __half*)&r0;
        const __half* h1 = (const __half*)&r1;
#pragma unroll
        for (int q = 0; q < 8; q++) acc[q] = fmaf(ww0, __half2float(h0[q]), acc[q]);
#pragma unroll
        for (int q = 0; q < 8; q++) acc[q] = fmaf(ww1, __half2float(h1[q]), acc[q]);
    };

    int G = (end - beg + STEP - 1) / STEP;   // granules (>=1: self loop)

    int   sa0, sa1, sb0, sb1, sc0, sc1, sd0, sd1;
    float wa0, wa1, wb0, wb1, wc0, wc1, wd0, wd1;
    uint4 ra0, ra1, rb0, rb1, rc0, rc1, rd0, rd1;

    // prologue: meta g0..g3, rows g0,g1
    meta(beg,            0, sa0, wa0); meta(beg,            1, sa1, wa1);
    meta(beg + STEP,     0, sb0, wb0); meta(beg + STEP,     1, sb1, wb1);
    rows(sa0, sa1, ra0, ra1);
    rows(sb0, sb1, rb0, rb1);
    meta(beg + 2 * STEP, 0, sc0, wc0); meta(beg + 2 * STEP, 1, sc1, wc1);
    meta(beg + 3 * STEP, 0, sd0, wd0); meta(beg + 3 * STEP, 1, sd1, wd1);

    int g = 0;
    int jf = beg + 4 * STEP;                 // next meta granule start to fetch
    while (true) {
        rows(sc0, sc1, rc0, rc1);            // issue g+2
        fmas(ra0, ra1, wa0, wa1);            // consume g
        if (++g >= G) break;
        meta(jf, 0, sa0, wa0); meta(jf, 1, sa1, wa1); jf += STEP;   // fetch g+4 (into freed A)

        rows(sd0, sd1, rd0, rd1);
        fmas(rb0, rb1, wb0, wb1);
        if (++g >= G) break;
        meta(jf, 0, sb0, wb0); meta(jf, 1, sb1, wb1); jf += STEP;

        rows(sa0, sa1, ra0, ra1);
        fmas(rc0, rc1, wc0, wc1);
        if (++g >= G) break;
        meta(jf, 0, sc0, wc0); meta(jf, 1, sc1, wc1); jf += STEP;

        rows(sb0, sb1, rb0, rb1);
        fmas(rd0, rd1, wd0, wd1);
        if (++g >= G) break;
        meta(jf, 0, sd0, wd0); meta(jf, 1, sd1, wd1); jf += STEP;
    }

    // combine sub-groups: xor-reduce down to sub==0
#pragma unroll
    for (int off = 32; off >= RV; off >>= 1) {
#pragma unroll
        for (int q = 0; q < 8; q++) acc[q] += __shfl_xor(acc[q], off);
    }
    if (sub == 0) {
        if constexpr (HEAD) {
            // feats fl*8 .. fl*8+7; fl<8 -> mu, fl>=8 -> logvar (chunks don't straddle 64)
            const float* bp = (fl < 8) ? (bmu + fl * 8) : (blv + (fl - 8) * 8);
#pragma unroll
            for (int q = 0; q < 8; q++) acc[q] += bp[q];
            float* op = (fl < 8) ? (mu + (size_t)node * 64 + fl * 8)
                                 : (lv + (size_t)node * 64 + (fl - 8) * 8);
            *(float4*)op = make_float4(acc[0], acc[1], acc[2], acc[3]);
            *(float4*)(op + 4) = make_float4(acc[4], acc[5], acc[6], acc[7]);
        } else {
            __half2 q0 = __floats2half2_rn(acc[0], acc[1]);
            __half2 q1 = __floats2half2_rn(acc[2], acc[3]);
            __half2 q2 = __floats2half2_rn(acc[4], acc[5]);
            __half2 q3 = __floats2half2_rn(acc[6], acc[7]);
            uint4 pk = make_uint4(*(unsigned*)&q0, *(unsigned*)&q1, *(unsigned*)&q2, *(unsigned*)&q3);
            *(uint4*)(out + (size_t)node * DIM + fl * 8) = pk;
        }
    }
}

// ---------------- MFMA GEMM: C[n x 128] = A[n x K] @ W[K x 128] (+bias, relu) ----------
// 256 thr = 4 waves, 64 rows/block (wave w -> rows m0+16w..+15), 8 col-tiles per wave.
// W^T fp16 staged in LDS ([col][k], 16/32 KB) with XOR swizzle ^((col&7)<<4) to kill the
// 16-way ds_read_b128 bank conflict. A fragments loaded direct from global (16B/lane).
// mfma_f32_16x16x32_f16: a[e]=A[lane&15][(lane>>4)*8+e], b[e]=W[(lane>>4)*8+e][col],
// d[r]=C[(lane>>4)*4+r][col=lane&15] (per verified gfx950 layout).

template <int K, bool BR>
__global__ __launch_bounds__(256) void mgemm_k(const __half* __restrict__ A,
                                               const __half* __restrict__ Wt,   // [128][K] fp16
                                               const float* __restrict__ bias,
                                               __half* __restrict__ C, int n) {
    __shared__ __align__(16) __half Wl[128 * K];
    int t = threadIdx.x;

    // stage Wt -> LDS (16B chunks, XOR swizzle on write; reads use the same XOR)
    constexpr int CHUNKS = 128 * K / 8;     // 16B chunks
    const uint4* Wg = (const uint4*)Wt;
    for (int i = t; i < CHUNKS; i += 256) {
        int g = i * 16;
        int col = g / (2 * K);
        uint4 v = Wg[i];
        *(uint4*)((char*)Wl + (g ^ ((col & 7) << 4))) = v;
    }
    __syncthreads();

    int lane = t & 63, w = t >> 6;
    int colb = lane & 15;
    int kq = (lane >> 4) * 8;
    int m0 = blockIdx.x * 64 + w * 16;
    int rowA = m0 + colb; if (rowA >= n) rowA = n - 1;
    const __half* Arow = A + (size_t)rowA * K + kq;

    f32x4 acc[8];
#pragma unroll
    for (int c = 0; c < 8; c++) acc[c] = (f32x4){0.f, 0.f, 0.f, 0.f};

    const char* wb = (const char*)Wl;
    int swz = (colb & 7) << 4;
    int off0 = colb * (2 * K) + kq * 2;

#pragma unroll
    for (int k0 = 0; k0 < K; k0 += 32) {
        f16x8 a = *(const f16x8*)(Arow + k0);
#pragma unroll
        for (int c = 0; c < 8; c++) {
            f16x8 b = *(const f16x8*)(wb + ((off0 + c * (32 * K) + k0 * 2) ^ swz));
            acc[c] = __builtin_amdgcn_mfma_f32_16x16x32_f16(a, b, acc[c], 0, 0, 0);
        }
    }

    int rbase = m0 + (lane >> 4) * 4;
#pragma unroll
    for (int c = 0; c < 8; c++) {
        int col = c * 16 + colb;
        float bv = BR ? bias[col] : 0.f;
#pragma unroll
        for (int r = 0; r < 4; r++) {
            int row = rbase + r;
            if (row < n) {
                float v = acc[c][r] + bv;
                if (BR) v = fmaxf(v, 0.f);
                C[(size_t)row * 128 + col] = __float2half(v);
            }
        }
    }
}

// ---------------- launch ----------------

extern "C" void kernel_launch(void* const* d_in, const int* in_sizes, int n_in,
                              void* d_out, int out_size, void* d_ws, size_t ws_size,
                              hipStream_t stream) {
    const int N = N_NODES, E = N_EDGES, ETOT = E_TOT;

    const float* x    = (const float*)d_in[0];
    const int*   ei   = (const int*)d_in[1];
    const int*   srcA = ei;
    const int*   dstA = ei + E;
    const float* W1   = (const float*)d_in[2];
    const float* b1   = (const float*)d_in[3];
    const float* W2   = (const float*)d_in[4];
    const float* b2   = (const float*)d_in[5];
    const float* Wmu  = (const float*)d_in[6];
    const float* bmu  = (const float*)d_in[7];
    const float* Wlv  = (const float*)d_in[8];
    const float* blv  = (const float*)d_in[9];
    float* out = (float*)d_out;

    // workspace carve-out
    char* ws = (char*)d_ws;
    size_t o = 0;
    auto alloc = [&](size_t bytes) -> void* {
        o = (o + 255) & ~(size_t)255;
        void* p = ws + o;
        o += bytes;
        return p;
    };
    int*    cnt    = (int*)alloc((size_t)N * 4);
    int*    rowptr = (int*)alloc((size_t)(N + 1) * 4);
    float*  dinv   = (float*)alloc((size_t)N * 4);
    int*    bsum   = (int*)alloc(512 * 4);
    int*    ebase  = (int*)alloc((size_t)(NB + 1) * 4);
    int*    bcur   = (int*)alloc((size_t)(NB + 1) * 4);
    int2*   em     = (int2*)alloc((size_t)ETOT * 8);          // packed {src, norm}
    int*    binned = (int*)alloc((size_t)E * 4);
    __half* x16    = (__half*)alloc((size_t)N * IN_DIM * 2);
    __half* B1     = (__half*)alloc((size_t)N * HIDDEN * 2);  // agg out / P
    __half* B2     = (__half*)alloc((size_t)N * HIDDEN * 2);  // gemm out
    __half* W1t    = (__half*)alloc(128 * 64 * 2);
    __half* W2t    = (__half*)alloc(128 * 128 * 2);
    __half* Wht    = (__half*)alloc(128 * 128 * 2);
    (void)ws_size;

    const int gN = (N + 255) / 256;          // 391
    const int gE = (E + 255) / 256;          // 6250
    const int gAgg = (N + 3) / 4;            // 25000 (4 nodes/block)
    const int gMg  = (N + 63) / 64;          // 1563 (64 rows/block)
    const int gCast = (N * IN_DIM / 8 + 255) / 256;

    // CSR build: node-level count+scan + contention-free two-phase fill; W prep; x cast
    hipMemsetAsync(cnt, 0, (size_t)N * 4, stream);
    count_k<<<gE, 256, 0, stream>>>(dstA, cnt, E);
    scan_block_k<<<gN, 256, 0, stream>>>(cnt, rowptr, bsum, dinv, N);
    scan_bsum_k<<<1, 512, 0, stream>>>(bsum, gN);
    scan_add_k<<<gN, 256, 0, stream>>>(rowptr, bsum, ebase, bcur, N, ETOT, E);
    binA_k<<<NBLK, 256, 0, stream>>>(srcA, dstA, bcur, binned, E);
    place_k<<<NB, 256, 0, stream>>>(binned, ebase, rowptr, dinv, em, N);
    wprep_k<<<160, 256, 0, stream>>>(W1, W2, Wmu, Wlv, W1t, W2t, Wht);
    cast16_k<<<gCast, 256, 0, stream>>>(x, x16, N * IN_DIM / 8);

    // layer 1: h = relu(Agg(x16) @ W1 + b1)        [agg 64-dim -> MFMA K=64]
    agg_k<64, false><<<gAgg, 256, 0, stream>>>(x16, rowptr, em, B1, nullptr, nullptr, nullptr, nullptr, N);
    mgemm_k<64, true><<<gMg, 256, 0, stream>>>(B1, W1t, b1, B2, N);

    // layer 2: h = relu(Agg(h) @ W2 + b2)          [agg 128-dim -> MFMA K=128]
    agg_k<128, false><<<gAgg, 256, 0, stream>>>(B2, rowptr, em, B1, nullptr, nullptr, nullptr, nullptr, N);
    mgemm_k<128, true><<<gMg, 256, 0, stream>>>(B1, W2t, b2, B2, N);

    // heads via linearity: P = h @ [Wmu|Wlv] (fp16), then out = Agg(P) + bias (fp32)
    mgemm_k<128, false><<<gMg, 256, 0, stream>>>(B2, Wht, nullptr, B1, N);
    agg_k<128, true><<<gAgg, 256, 0, stream>>>(B1, rowptr, em, nullptr, bmu, blv,
                                               out, out + (size_t)N * Z_DIM, N);
}

// Round 7
// 425.682 us; speedup vs baseline: 1.0117x; 1.0117x over previous
//
#include <hip/hip_runtime.h>
#include <hip/hip_fp16.h>
#include <cstddef>

// Problem constants (match reference)
#define N_NODES 100000
#define N_EDGES 1600000
#define E_TOT   (N_EDGES + N_NODES)   // edges + self loops = 1,700,000
#define IN_DIM  64
#define HIDDEN  128
#define Z_DIM   64

// dst-buckets for locality-preserving fill
#define BN 128
#define NB ((N_NODES + BN - 1) / BN)   // 782
#define NBLK 256                        // chunk blocks for binA
#define GN  ((N_NODES + 255) / 256)     // 391 scan blocks

// em rows padded to multiple of 16 entries (self + edges + {node,0} pads)
#define EM_CAP (E_TOT + 15 * N_NODES + 64)

using f16x8 = __attribute__((ext_vector_type(8))) _Float16;
using f32x4 = __attribute__((ext_vector_type(4))) float;

// ---------------- prep: x cast + W prep + cnt zero (one kernel, 3 sections) -----------

__global__ __launch_bounds__(256) void prep_k(const float* __restrict__ x, __half* __restrict__ x16,
                                              const float* __restrict__ W1, const float* __restrict__ W2,
                                              const float* __restrict__ Wmu, const float* __restrict__ Wlv,
                                              __half* __restrict__ W1t, __half* __restrict__ W2t,
                                              __half* __restrict__ Wht, int* __restrict__ cnt) {
    int i = blockIdx.x * 256 + threadIdx.x;
    const int CAST = N_NODES * IN_DIM / 8;        // 800000
    if (i < CAST) {
        const float4* in4 = (const float4*)x;
        float4 a = in4[2 * i], b = in4[2 * i + 1];
        __half2 h0 = __floats2half2_rn(a.x, a.y);
        __half2 h1 = __floats2half2_rn(a.z, a.w);
        __half2 h2 = __floats2half2_rn(b.x, b.y);
        __half2 h3 = __floats2half2_rn(b.z, b.w);
        uint4 pk = make_uint4(*(unsigned*)&h0, *(unsigned*)&h1, *(unsigned*)&h2, *(unsigned*)&h3);
        ((uint4*)x16)[i] = pk;
        return;
    }
    int j = i - CAST;
    if (j < 128 * 64) {
        int col = j >> 6, k = j & 63;
        W1t[j] = __float2half(W1[k * 128 + col]);
        return;
    }
    int m = j - 128 * 64;
    if (m < 128 * 128) {
        int col = m >> 7, k = m & 127;
        W2t[m] = __float2half(W2[k * 128 + col]);
        return;
    }
    int h = m - 128 * 128;
    if (h < 128 * 128) {
        int col = h >> 7, k = h & 127;
        Wht[h] = __float2half(col < 64 ? Wmu[k * 64 + col] : Wlv[k * 64 + (col - 64)]);
        return;
    }
    int z = h - 128 * 128;
    if (z < N_NODES / 4) ((int4*)cnt)[z] = make_int4(0, 0, 0, 0);
}

// ---------------- CSR build ----------------

// per-node degree count, int4 edge reads (4 dsts/thread), fire-and-forget atomics
__global__ __launch_bounds__(256) void count4_k(const int* __restrict__ dst, int* cnt, int e4) {
    int i = blockIdx.x * 256 + threadIdx.x;
    if (i < e4) {
        int4 d = ((const int4*)dst)[i];
        atomicAdd(&cnt[d.x], 1);
        atomicAdd(&cnt[d.y], 1);
        atomicAdd(&cnt[d.z], 1);
        atomicAdd(&cnt[d.w], 1);
    }
}

// dual block-scan: padded degree (ceil((cnt+1)/16)*16) -> rowptr (local excl), raw edge
// count -> rawAt[bucket] locals + bsum {padIncl, rawIncl}; emits dinv = rsqrt(deg).
__global__ __launch_bounds__(256) void scan_block_k(const int* __restrict__ cnt, int* __restrict__ rowptr,
                                                    int2* __restrict__ bsum, int* __restrict__ rawAt,
                                                    float* __restrict__ dinv, int n) {
    __shared__ int sp[256], sr[256];
    int tid = threadIdx.x;
    int i = blockIdx.x * 256 + tid;
    int deg = (i < n) ? cnt[i] + 1 : 0;           // incl self loop
    int pad = (deg + 15) & ~15;                   // 0 stays 0
    int raw = (i < n) ? deg - 1 : 0;              // edges only
    if (i < n) dinv[i] = rsqrtf((float)deg);
    sp[tid] = pad; sr[tid] = raw;
    __syncthreads();
#pragma unroll
    for (int off = 1; off < 256; off <<= 1) {
        int t1 = (tid >= off) ? sp[tid - off] : 0;
        int t2 = (tid >= off) ? sr[tid - off] : 0;
        __syncthreads();
        sp[tid] += t1; sr[tid] += t2;
        __syncthreads();
    }
    if (i < n) rowptr[i] = sp[tid] - pad;         // padded exclusive (local)
    if (i < n && tid == 0)   rawAt[i >> 7] = 0;                // raw excl at bucket start
    if (i < n && tid == 128) rawAt[i >> 7] = sr[127];          // inclusive up to 127
    if (tid == 255) bsum[blockIdx.x] = make_int2(sp[255], sr[255]);
}

// merged bsum-scan + add: 512 threads scan all block sums in LDS, 256 apply to rowptr;
// bucket bases ebase/bcur = raw edge prefix (binned space). No separate bsum kernel.
__global__ __launch_bounds__(512) void scan_addm_k(int* __restrict__ rowptr, const int2* __restrict__ bsum,
                                                   const int* __restrict__ rawAt, int* __restrict__ ebase,
                                                   int* __restrict__ bcur, int n, int e, int nb) {
    __shared__ int sp[512], sr[512];
    __shared__ int tot;
    int tid = threadIdx.x;
    int2 v = (tid < nb) ? bsum[tid] : make_int2(0, 0);
    sp[tid] = v.x; sr[tid] = v.y;
    __syncthreads();
#pragma unroll
    for (int off = 1; off < 512; off <<= 1) {
        int t1 = (tid >= off) ? sp[tid - off] : 0;
        int t2 = (tid >= off) ? sr[tid - off] : 0;
        __syncthreads();
        sp[tid] += t1; sr[tid] += t2;
        __syncthreads();
    }
    if (tid == 511) tot = sp[511];                // total padded entries
    __syncthreads();
    sp[tid] -= v.x; sr[tid] -= v.y;               // exclusive
    __syncthreads();
    if (tid < 256) {
        int i = blockIdx.x * 256 + tid;
        if (i < n) {
            int val = rowptr[i] + sp[blockIdx.x];
            rowptr[i] = val;
            if ((i & 127) == 0) {
                int b = i >> 7;
                int eb = rawAt[b] + sr[b >> 1];
                ebase[b] = eb;
                bcur[b] = eb;
            }
        }
        if (i == 0) { rowptr[n] = tot; ebase[NB] = e; }
    }
}

// Phase A: chunked binning. LDS bucket-hist per block; ONE with-return global atomic per
// (block,bucket) (200K total — no contention stall); place chunk into bucket-contiguous
// binned[] via LDS cursors. Packed 4B: {local_dst(7b) << 17 | src(17b)}.
__global__ __launch_bounds__(256) void binA_k(const int* __restrict__ src, const int* __restrict__ dst,
                                              int* __restrict__ bcur, int* __restrict__ binned, int e) {
    __shared__ int hist[NB];
    __shared__ int cur[NB];
    int t = threadIdx.x;
    int ch = (e + gridDim.x - 1) / gridDim.x;
    int i0 = blockIdx.x * ch;
    int i1 = i0 + ch; if (i1 > e) i1 = e;

    for (int b = t; b < NB; b += 256) hist[b] = 0;
    __syncthreads();
    for (int i = i0 + t; i < i1; i += 256)
        atomicAdd(&hist[dst[i] >> 7], 1);
    __syncthreads();
    for (int b = t; b < NB; b += 256) {
        int h = hist[b];
        cur[b] = h ? atomicAdd(&bcur[b], h) : 0;
    }
    __syncthreads();
    for (int i = i0 + t; i < i1; i += 256) {
        int s = src[i], d = dst[i];
        int p = atomicAdd(&cur[d >> 7], 1);
        binned[p] = ((d & 127) << 17) | s;
    }
}

// Phase B: one block per bucket. Per-node LDS cursors seeded from (padded) rowptr; self
// first, edges via cursor, then {node, 0} pads to the next padded start. All em writes
// for the bucket come from ONE CU -> full-line merge in its L2.
__global__ __launch_bounds__(256) void place_k(const int* __restrict__ binned, const int* __restrict__ ebase,
                                               const int* __restrict__ rowptr, const float* __restrict__ dinv,
                                               int2* __restrict__ em, int n) {
    __shared__ int cur[BN];
    __shared__ float sdv[BN];
    int b = blockIdx.x, t = threadIdx.x;
    int n0 = b * BN;
    int nn = n - n0; if (nn > BN) nn = BN;
    if (t < nn) {
        int rp = rowptr[n0 + t];
        float dv = dinv[n0 + t];
        sdv[t] = dv;
        em[rp] = make_int2(n0 + t, __float_as_int(dv * dv));   // self loop first
        cur[t] = rp + 1;
    }
    __syncthreads();
    int e0 = ebase[b], e1 = ebase[b + 1];
    for (int i = e0 + t; i < e1; i += 256) {
        int pk = binned[i];
        int ld = pk >> 17, s = pk & 0x1FFFF;
        int q = atomicAdd(&cur[ld], 1);
        em[q] = make_int2(s, __float_as_int(dinv[s] * sdv[ld]));
    }
    __syncthreads();
    if (t < nn) {
        int pe = rowptr[n0 + t + 1];              // next padded start
        int node = n0 + t;
        for (int p = cur[t]; p < pe; p++) em[p] = make_int2(node, 0);
    }
}

// ---------------- Aggregation (gather): fp16 rows, fp32 accumulate ----------------
// One node per wave; granule = 2 slots (STEP edges). 4-phase rotated software pipeline:
// body(p) issues rows(g+2), FMAs granule g, fetches meta(g+4). em rows are PADDED to a
// multiple of 16 with {node, w=0} -> inner loop is branch-free with NO per-slot clamp
// compare/select; G = (end-beg)/STEP exactly. Prefetch overrun past the last node is
// clamped to the final em entry (never consumed; keeps indices valid).

template <int DIM, bool HEAD>
__global__ __launch_bounds__(256) void agg_k(const __half* __restrict__ H, const int* __restrict__ rowptr,
                                             const int2* __restrict__ em, __half* __restrict__ out,
                                             const float* __restrict__ bmu, const float* __restrict__ blv,
                                             float* __restrict__ mu, float* __restrict__ lv, int n) {
    int node = (int)((blockIdx.x * 256 + threadIdx.x) >> 6);
    if (node >= n) return;
    int lane = threadIdx.x & 63;
    int beg = rowptr[node], end = rowptr[node + 1];
    int lastIdx = rowptr[n] - 1;
    const uint4* H4 = (const uint4*)H;

    constexpr int RV   = DIM / 8;            // 16B-chunks per row (128->16, 64->8)
    constexpr int SUBS = 64 / RV;            // parallel edge slots (4 or 8)
    constexpr int STEP = SUBS * 2;           // edges per granule (8 or 16)
    int sub = lane / RV;
    int fl  = lane % RV;

    float acc[8];
#pragma unroll
    for (int q = 0; q < 8; q++) acc[q] = 0.f;

    auto meta = [&](int j, int p, int& s, float& w) {
        int ci = j + SUBS * p + sub;
        ci = min(ci, lastIdx);               // prefetch-overrun safety only
        int2 e = em[ci];
        s = e.x;
        w = __int_as_float(e.y);             // pads carry w = 0
    };
    auto rows = [&](int s0, int s1, uint4& r0, uint4& r1) {
        r0 = H4[(size_t)s0 * RV + fl];
        r1 = H4[(size_t)s1 * RV + fl];
    };
    auto fmas = [&](const uint4& r0, const uint4& r1, float ww0, float ww1) {
        const __half* h0 = (const __half*)&r0;
        const __half* h1 = (const __half*)&r1;
#pragma unroll
        for (int q = 0; q < 8; q++) acc[q] = fmaf(ww0, __half2float(h0[q]), acc[q]);
#pragma unroll
        for (int q = 0; q < 8; q++) acc[q] = fmaf(ww1, __half2float(h1[q]), acc[q]);
    };

    int G = (end - beg) / STEP;              // exact (padded); >= 1

    int   sa0, sa1, sb0, sb1, sc0, sc1, sd0, sd1;
    float wa0, wa1, wb0, wb1, wc0, wc1, wd0, wd1;
    uint4 ra0, ra1, rb0, rb1, rc0, rc1, rd0, rd1;

    // prologue: meta g0..g3, rows g0,g1
    meta(beg,            0, sa0, wa0); meta(beg,            1, sa1, wa1);
    meta(beg + STEP,     0, sb0, wb0); meta(beg + STEP,     1, sb1, wb1);
    rows(sa0, sa1, ra0, ra1);
    rows(sb0, sb1, rb0, rb1);
    meta(beg + 2 * STEP, 0, sc0, wc0); meta(beg + 2 * STEP, 1, sc1, wc1);
    meta(beg + 3 * STEP, 0, sd0, wd0); meta(beg + 3 * STEP, 1, sd1, wd1);

    int g = 0;
    int jf = beg + 4 * STEP;                 // next meta granule start to fetch
    while (true) {
        rows(sc0, sc1, rc0, rc1);            // issue g+2
        fmas(ra0, ra1, wa0, wa1);            // consume g
        if (++g >= G) break;
        meta(jf, 0, sa0, wa0); meta(jf, 1, sa1, wa1); jf += STEP;   // fetch g+4

        rows(sd0, sd1, rd0, rd1);
        fmas(rb0, rb1, wb0, wb1);
        if (++g >= G) break;
        meta(jf, 0, sb0, wb0); meta(jf, 1, sb1, wb1); jf += STEP;

        rows(sa0, sa1, ra0, ra1);
        fmas(rc0, rc1, wc0, wc1);
        if (++g >= G) break;
        meta(jf, 0, sc0, wc0); meta(jf, 1, sc1, wc1); jf += STEP;

        rows(sb0, sb1, rb0, rb1);
        fmas(rd0, rd1, wd0, wd1);
        if (++g >= G) break;
        meta(jf, 0, sd0, wd0); meta(jf, 1, sd1, wd1); jf += STEP;
    }

    // combine sub-groups: xor-reduce down to sub==0
#pragma unroll
    for (int off = 32; off >= RV; off >>= 1) {
#pragma unroll
        for (int q = 0; q < 8; q++) acc[q] += __shfl_xor(acc[q], off);
    }
    if (sub == 0) {
        if constexpr (HEAD) {
            // feats fl*8 .. fl*8+7; fl<8 -> mu, fl>=8 -> logvar (chunks don't straddle 64)
            const float* bp = (fl < 8) ? (bmu + fl * 8) : (blv + (fl - 8) * 8);
#pragma unroll
            for (int q = 0; q < 8; q++) acc[q] += bp[q];
            float* op = (fl < 8) ? (mu + (size_t)node * 64 + fl * 8)
                                 : (lv + (size_t)node * 64 + (fl - 8) * 8);
            *(float4*)op = make_float4(acc[0], acc[1], acc[2], acc[3]);
            *(float4*)(op + 4) = make_float4(acc[4], acc[5], acc[6], acc[7]);
        } else {
            __half2 q0 = __floats2half2_rn(acc[0], acc[1]);
            __half2 q1 = __floats2half2_rn(acc[2], acc[3]);
            __half2 q2 = __floats2half2_rn(acc[4], acc[5]);
            __half2 q3 = __floats2half2_rn(acc[6], acc[7]);
            uint4 pk = make_uint4(*(unsigned*)&q0, *(unsigned*)&q1, *(unsigned*)&q2, *(unsigned*)&q3);
            *(uint4*)(out + (size_t)node * DIM + fl * 8) = pk;
        }
    }
}

// ---------------- MFMA GEMM: C[n x 128] = A[n x K] @ W[K x 128] (+bias, relu) ----------
// 256 thr = 4 waves, 64 rows/block (wave w -> rows m0+16w..+15), 8 col-tiles per wave.
// W^T fp16 staged in LDS ([col][k], 16/32 KB) with XOR swizzle ^((col&7)<<4) to kill the
// 16-way ds_read_b128 bank conflict. A fragments loaded direct from global (16B/lane).
// mfma_f32_16x16x32_f16: a[e]=A[lane&15][(lane>>4)*8+e], b[e]=W[(lane>>4)*8+e][col],
// d[r]=C[(lane>>4)*4+r][col=lane&15] (per verified gfx950 layout).

template <int K, bool BR>
__global__ __launch_bounds__(256) void mgemm_k(const __half* __restrict__ A,
                                               const __half* __restrict__ Wt,   // [128][K] fp16
                                               const float* __restrict__ bias,
                                               __half* __restrict__ C, int n) {
    __shared__ __align__(16) __half Wl[128 * K];
    int t = threadIdx.x;

    // stage Wt -> LDS (16B chunks, XOR swizzle on write; reads use the same XOR)
    constexpr int CHUNKS = 128 * K / 8;     // 16B chunks
    const uint4* Wg = (const uint4*)Wt;
    for (int i = t; i < CHUNKS; i += 256) {
        int g = i * 16;
        int col = g / (2 * K);
        uint4 v = Wg[i];
        *(uint4*)((char*)Wl + (g ^ ((col & 7) << 4))) = v;
    }
    __syncthreads();

    int lane = t & 63, w = t >> 6;
    int colb = lane & 15;
    int kq = (lane >> 4) * 8;
    int m0 = blockIdx.x * 64 + w * 16;
    int rowA = m0 + colb; if (rowA >= n) rowA = n - 1;
    const __half* Arow = A + (size_t)rowA * K + kq;

    f32x4 acc[8];
#pragma unroll
    for (int c = 0; c < 8; c++) acc[c] = (f32x4){0.f, 0.f, 0.f, 0.f};

    const char* wb = (const char*)Wl;
    int swz = (colb & 7) << 4;
    int off0 = colb * (2 * K) + kq * 2;

#pragma unroll
    for (int k0 = 0; k0 < K; k0 += 32) {
        f16x8 a = *(const f16x8*)(Arow + k0);
#pragma unroll
        for (int c = 0; c < 8; c++) {
            f16x8 b = *(const f16x8*)(wb + ((off0 + c * (32 * K) + k0 * 2) ^ swz));
            acc[c] = __builtin_amdgcn_mfma_f32_16x16x32_f16(a, b, acc[c], 0, 0, 0);
        }
    }

    int rbase = m0 + (lane >> 4) * 4;
#pragma unroll
    for (int c = 0; c < 8; c++) {
        int col = c * 16 + colb;
        float bv = BR ? bias[col] : 0.f;
#pragma unroll
        for (int r = 0; r < 4; r++) {
            int row = rbase + r;
            if (row < n) {
                float v = acc[c][r] + bv;
                if (BR) v = fmaxf(v, 0.f);
                C[(size_t)row * 128 + col] = __float2half(v);
            }
        }
    }
}

// ---------------- launch ----------------

extern "C" void kernel_launch(void* const* d_in, const int* in_sizes, int n_in,
                              void* d_out, int out_size, void* d_ws, size_t ws_size,
                              hipStream_t stream) {
    const int N = N_NODES, E = N_EDGES;

    const float* x    = (const float*)d_in[0];
    const int*   ei   = (const int*)d_in[1];
    const int*   srcA = ei;
    const int*   dstA = ei + E;
    const float* W1   = (const float*)d_in[2];
    const float* b1   = (const float*)d_in[3];
    const float* W2   = (const float*)d_in[4];
    const float* b2   = (const float*)d_in[5];
    const float* Wmu  = (const float*)d_in[6];
    const float* bmu  = (const float*)d_in[7];
    const float* Wlv  = (const float*)d_in[8];
    const float* blv  = (const float*)d_in[9];
    float* out = (float*)d_out;

    // workspace carve-out
    char* ws = (char*)d_ws;
    size_t o = 0;
    auto alloc = [&](size_t bytes) -> void* {
        o = (o + 255) & ~(size_t)255;
        void* p = ws + o;
        o += bytes;
        return p;
    };
    int*    cnt    = (int*)alloc((size_t)N * 4);
    int*    rowptr = (int*)alloc((size_t)(N + 1) * 4);
    float*  dinv   = (float*)alloc((size_t)N * 4);
    int2*   bsum   = (int2*)alloc(512 * 8);
    int*    rawAt  = (int*)alloc((size_t)NB * 4);
    int*    ebase  = (int*)alloc((size_t)(NB + 1) * 4);
    int*    bcur   = (int*)alloc((size_t)(NB + 1) * 4);
    int2*   em     = (int2*)alloc((size_t)EM_CAP * 8);        // padded {src, norm}
    int*    binned = (int*)alloc((size_t)E * 4);
    __half* x16    = (__half*)alloc((size_t)N * IN_DIM * 2);
    __half* B1     = (__half*)alloc((size_t)N * HIDDEN * 2);  // agg out / P
    __half* B2     = (__half*)alloc((size_t)N * HIDDEN * 2);  // gemm out
    __half* W1t    = (__half*)alloc(128 * 64 * 2);
    __half* W2t    = (__half*)alloc(128 * 128 * 2);
    __half* Wht    = (__half*)alloc(128 * 128 * 2);
    (void)ws_size;

    const int PREP_T = N * IN_DIM / 8 + 128 * 64 + 128 * 128 + 128 * 128 + N / 4;
    const int gPrep = (PREP_T + 255) / 256;
    const int gC4  = (E / 4 + 255) / 256;    // 1563
    const int gAgg = (N + 3) / 4;            // 25000 (4 nodes/block)
    const int gMg  = (N + 63) / 64;          // 1563 (64 rows/block)

    // prep (cast + W prep + cnt zero) then CSR build (12 launches total)
    prep_k<<<gPrep, 256, 0, stream>>>(x, x16, W1, W2, Wmu, Wlv, W1t, W2t, Wht, cnt);
    count4_k<<<gC4, 256, 0, stream>>>(dstA, cnt, E / 4);
    scan_block_k<<<GN, 256, 0, stream>>>(cnt, rowptr, bsum, rawAt, dinv, N);
    scan_addm_k<<<GN, 512, 0, stream>>>(rowptr, bsum, rawAt, ebase, bcur, N, E, GN);
    binA_k<<<NBLK, 256, 0, stream>>>(srcA, dstA, bcur, binned, E);
    place_k<<<NB, 256, 0, stream>>>(binned, ebase, rowptr, dinv, em, N);

    // layer 1: h = relu(Agg(x16) @ W1 + b1)        [agg 64-dim -> MFMA K=64]
    agg_k<64, false><<<gAgg, 256, 0, stream>>>(x16, rowptr, em, B1, nullptr, nullptr, nullptr, nullptr, N);
    mgemm_k<64, true><<<gMg, 256, 0, stream>>>(B1, W1t, b1, B2, N);

    // layer 2: h = relu(Agg(h) @ W2 + b2)          [agg 128-dim -> MFMA K=128]
    agg_k<128, false><<<gAgg, 256, 0, stream>>>(B2, rowptr, em, B1, nullptr, nullptr, nullptr, nullptr, N);
    mgemm_k<128, true><<<gMg, 256, 0, stream>>>(B1, W2t, b2, B2, N);

    // heads via linearity: P = h @ [Wmu|Wlv] (fp16), then out = Agg(P) + bias (fp32)
    mgemm_k<128, false><<<gMg, 256, 0, stream>>>(B2, Wht, nullptr, B1, N);
    agg_k<128, true><<<gAgg, 256, 0, stream>>>(B1, rowptr, em, nullptr, bmu, blv,
                                               out, out + (size_t)N * Z_DIM, N);
}